// Round 9
// baseline (231.739 us; speedup 1.0000x reference)
//
#include <hip/hip_runtime.h>
#include <hip/hip_bf16.h>

// Problem constants
#define BATCH 8
#define CCH   256
#define NPOS  4096
#define CQK   32

typedef __attribute__((ext_vector_type(8))) short short8;   // 8 bf16 = 4 VGPRs (MFMA A/B frag)
typedef __attribute__((ext_vector_type(4))) float f32x4;    // MFMA C/D frag

__device__ inline unsigned short f2b(float f) {
    __hip_bfloat16 h = __float2bfloat16(f);
    return *reinterpret_cast<unsigned short*>(&h);
}

// ---------------------------------------------------------------------------
// Fragment-block swizzled layouts.  A 512-short block = one 16x32 MFMA
// operand tile; lane (quad,ln) reads short8 at block*512 + (quad*16+ln)*8.
//   qb/kb: qk_addr  — [b][n>>4][c>>3][n&15][c&7]           (c < 32)
//   obb:   xt_addr  — [b][n>>4][c>>5][(c>>3)&3][n&15][c&7] (c < 256)
//   vb:    v_addr   — [b][j>>5][c>>4][(j>>3)&3][c&15][j&7]
//   wsw:   wsw_addr — og-unit = 16 rows x 256 c; og: q=0..1,k=2..3,v=4..19,f=20..35
// ---------------------------------------------------------------------------
__device__ inline size_t qk_addr(int b, int n, int c) {
    return ((((size_t)b * 256 + (n >> 4)) * 4 + (c >> 3)) * 16 + (n & 15)) * 8 + (c & 7);
}
__device__ inline size_t xt_addr(int b, int n, int c) {
    return (((size_t)b * 256 + (n >> 4)) * 8 + (c >> 5)) * 512
           + (((c >> 3) & 3) * 16 + (n & 15)) * 8 + (c & 7);
}
__device__ inline size_t v_addr(int b, int c, int j) {
    return (((((size_t)b * 128 + (j >> 5)) * 16 + (c >> 4)) * 4 + ((j >> 3) & 3)) * 16 + (c & 15)) * 8 + (j & 7);
}
__device__ inline size_t wsw_addr(int og, int c, int ol) {
    return ((size_t)(og * 8 + (c >> 5))) * 512 + (((c >> 3) & 3) * 16 + ol) * 8 + (c & 7);
}

// ---------------------------------------------------------------------------
// Kernel 0: weights -> wsw bf16 frag blocks (36 blocks, tiny).
// ---------------------------------------------------------------------------
__global__ __launch_bounds__(256, 4)
void wprep_kernel(const float* __restrict__ Wq, const float* __restrict__ Wk,
                  const float* __restrict__ Wv, const float* __restrict__ Wf,
                  unsigned short* __restrict__ wsw)
{
    const int og = blockIdx.x;           // 0..35
    const int t  = threadIdx.x;
    const float* src; int orow;
    if (og < 2)       { src = Wq; orow = og * 16; }
    else if (og < 4)  { src = Wk; orow = (og - 2) * 16; }
    else if (og < 20) { src = Wv; orow = (og - 4) * 16; }
    else              { src = Wf; orow = (og - 20) * 16; }
    #pragma unroll
    for (int e = 0; e < 16; ++e) {
        int idx = t + e * 256;
        int ol = idx >> 8, c = idx & 255;
        wsw[wsw_addr(og, c, ol)] = f2b(src[(orow + ol) * 256 + c]);
    }
}

// ---------------------------------------------------------------------------
// Kernel 1: fused QKV — block = (64-n tile, b).  Stage x[256c][64n] -> LDS in
// bf16 frag layout (one barrier), hold the wave's 8 x-frags in registers,
// then 20 o-tiles x 8 MFMAs against L2-resident wsw frags.  Replaces R8's
// separate x-transpose pass + xt round-trip (34 MB eliminated).
// ---------------------------------------------------------------------------
__global__ __launch_bounds__(256, 3)
void qkv_kernel(const float* __restrict__ x,
                const unsigned short* __restrict__ wsw,
                const float* __restrict__ bq, const float* __restrict__ bk,
                const float* __restrict__ bv,
                unsigned short* __restrict__ qb, unsigned short* __restrict__ kb,
                unsigned short* __restrict__ vb)
{
    __shared__ unsigned short xl[32 * 512];      // 32 KB: 4 n-tiles x 8 c-blocks

    const int nt = blockIdx.x;           // 0..63
    const int b  = blockIdx.y;           // 0..7
    const int t  = threadIdx.x;
    const int w    = t >> 6;
    const int quad = (t >> 4) & 3;
    const int ln   = t & 15;
    const int lofs = (quad * 16 + ln) * 8;
    const int n0 = nt * 64;

    // ---- stage x -> LDS bf16 frag layout ----
    #pragma unroll
    for (int ch = 0; ch < 16; ++ch) {
        int idx = t + ch * 256;              // 0..4095
        int c   = idx >> 4;
        int n4  = (idx & 15) * 4;
        float4 v = *(const float4*)(x + (size_t)(b * 256 + c) * 4096 + n0 + n4);
        #pragma unroll
        for (int jj = 0; jj < 4; ++jj) {
            int nl  = n4 + jj;
            int off = ((nl >> 4) * 8 + (c >> 5)) * 512
                    + (((c >> 3) & 3) * 16 + (nl & 15)) * 8 + (c & 7);
            xl[off] = f2b(((const float*)&v)[jj]);
        }
    }
    __syncthreads();

    // ---- wave's x-frags (n-tile = w), resident for all 20 o-tiles ----
    short8 xf[8];
    #pragma unroll
    for (int kk = 0; kk < 8; ++kk)
        xf[kk] = *(const short8*)&xl[(w * 8 + kk) * 512 + lofs];

    // ---- q/k: og 0..3, A = W (o-rows), B = x ----
    #pragma unroll
    for (int og = 0; og < 4; ++og) {
        const float* bias = (og < 2) ? bq : bk;
        const int cb16 = (og & 1) * 16;
        f32x4 acc = {bias[cb16 + quad * 4 + 0], bias[cb16 + quad * 4 + 1],
                     bias[cb16 + quad * 4 + 2], bias[cb16 + quad * 4 + 3]};
        #pragma unroll
        for (int kk = 0; kk < 8; ++kk) {
            short8 af = *(const short8*)(wsw + (size_t)(og * 8 + kk) * 512 + lofs);
            acc = __builtin_amdgcn_mfma_f32_16x16x32_bf16(af, xf[kk], acc, 0, 0, 0);
        }
        ushort4 s = {f2b(acc[0]), f2b(acc[1]), f2b(acc[2]), f2b(acc[3])};
        unsigned short* dst = (og < 2) ? qb : kb;
        *(ushort4*)(dst + qk_addr(b, n0 + w * 16 + ln, cb16 + quad * 4)) = s;
    }

    // ---- v: og 4..19, A = x (j-rows), B = Wv (c-cols) ----
    #pragma unroll
    for (int og = 4; og < 20; ++og) {
        const int c = (og - 4) * 16 + ln;
        const float bb = bv[c];
        f32x4 acc = {bb, bb, bb, bb};
        #pragma unroll
        for (int kk = 0; kk < 8; ++kk) {
            short8 bfr = *(const short8*)(wsw + (size_t)(og * 8 + kk) * 512 + lofs);
            acc = __builtin_amdgcn_mfma_f32_16x16x32_bf16(xf[kk], bfr, acc, 0, 0, 0);
        }
        ushort4 s = {f2b(acc[0]), f2b(acc[1]), f2b(acc[2]), f2b(acc[3])};
        *(ushort4*)(vb + v_addr(b, c, n0 + w * 16 + quad * 4)) = s;
    }
}

// ---------------------------------------------------------------------------
// Kernel 2: fused flash attention, software-pipelined, unroll-2 ping-pong.
// R9: frag sets indexed by compile-time parity (no rotation movs — R8 burned
// ~48 v_mov/iter, VALUBusy 38%).  S computed TRANSPOSED (A=K, B=Q) so each
// thread's 4 exp results are consecutive j -> one ds_write_b64 per jc
// (16 ds_write_u16 -> 4 ds_write_b64), and the softmax row-sum is one scalar
// per thread (reduce across quads via xor 16/32).
// ---------------------------------------------------------------------------
__global__ __launch_bounds__(256, 2)
void attn_kernel(const unsigned short* __restrict__ qb,
                 const unsigned short* __restrict__ kb,
                 const unsigned short* __restrict__ vb,
                 unsigned short* __restrict__ obb)
{
    __shared__ unsigned short plds[2][64][72];   // [buf][i][j], +8 pad
    __shared__ float lred[64];

    const int bid  = blockIdx.x;
    const int b    = bid & 7;                    // XCD swizzle
    const int i0   = (bid >> 3) * 64;
    const int t    = threadIdx.x;
    const int w    = t >> 6;
    const int lane = t & 63;
    const int quad = lane >> 4;
    const int ln   = lane & 15;

    const int lofs = (quad * 16 + ln) * 8;

    const short8 qfrag = *(const short8*)(qb + (((size_t)b * 256 + ((i0 >> 4) + w)) * 512) + lofs);

    f32x4 acc[4][4];                             // [i-tile][c-chunk]
    #pragma unroll
    for (int it = 0; it < 4; ++it)
        #pragma unroll
        for (int cc = 0; cc < 4; ++cc) acc[it][cc] = (f32x4){0.f, 0.f, 0.f, 0.f};
    float accl = 0.f;                            // row-sum partial for i = i0+w*16+ln

    const unsigned short* kbase = kb + (size_t)b * 256 * 512;
    const unsigned short* vbase = vb + (size_t)b * 128 * 8192;

    // ---- prologue: prefetch j0 = 0 into set 0 ----
    short8 kf[2][4], vf[2][4][2];
    #pragma unroll
    for (int jc = 0; jc < 4; ++jc)
        kf[0][jc] = *(const short8*)(kbase + (size_t)jc * 512 + lofs);
    #pragma unroll
    for (int cc = 0; cc < 4; ++cc) {
        vf[0][cc][0] = *(const short8*)(vbase + (w * 4 + cc) * 512 + lofs);
        vf[0][cc][1] = *(const short8*)(vbase + 8192 + (w * 4 + cc) * 512 + lofs);
    }

    for (int j0 = 0; j0 < 4096; j0 += 128) {
        #pragma unroll
        for (int u = 0; u < 2; ++u) {
            const int jnxt = (j0 + u * 64 + 64) & 4095;
            // ---- prefetch next 64-j into the other set ----
            #pragma unroll
            for (int jc = 0; jc < 4; ++jc)
                kf[u ^ 1][jc] = *(const short8*)(kbase + (size_t)((jnxt >> 4) + jc) * 512 + lofs);
            const unsigned short* vtn = vbase + (size_t)(jnxt >> 5) * 8192;
            #pragma unroll
            for (int cc = 0; cc < 4; ++cc) {
                vf[u ^ 1][cc][0] = *(const short8*)(vtn + (w * 4 + cc) * 512 + lofs);
                vf[u ^ 1][cc][1] = *(const short8*)(vtn + 8192 + (w * 4 + cc) * 512 + lofs);
            }
            // ---- S^T = K Q^T : D[j][i], row=j=quad*4+r, col=i=ln ----
            f32x4 s[4];
            #pragma unroll
            for (int jc = 0; jc < 4; ++jc)
                s[jc] = __builtin_amdgcn_mfma_f32_16x16x32_bf16(kf[u][jc], qfrag,
                         (f32x4){0.f, 0.f, 0.f, 0.f}, 0, 0, 0);
            // ---- exp, pack 4 consecutive j, one b64 write per jc ----
            #pragma unroll
            for (int jc = 0; jc < 4; ++jc) {
                float p0 = __expf(s[jc][0]);
                float p1 = __expf(s[jc][1]);
                float p2 = __expf(s[jc][2]);
                float p3 = __expf(s[jc][3]);
                accl += (p0 + p1) + (p2 + p3);
                uint2 uu;
                uu.x = (unsigned)f2b(p0) | ((unsigned)f2b(p1) << 16);
                uu.y = (unsigned)f2b(p2) | ((unsigned)f2b(p3) << 16);
                *(uint2*)&plds[u][w * 16 + ln][jc * 16 + quad * 4] = uu;
            }
            __syncthreads();
            // ---- O += P V with resident V : 32 MFMAs ----
            #pragma unroll
            for (int it = 0; it < 4; ++it) {
                const short8 pf0 = *(const short8*)&plds[u][it * 16 + ln][quad * 8];
                const short8 pf1 = *(const short8*)&plds[u][it * 16 + ln][32 + quad * 8];
                #pragma unroll
                for (int cc = 0; cc < 4; ++cc) {
                    acc[it][cc] = __builtin_amdgcn_mfma_f32_16x16x32_bf16(pf0, vf[u][cc][0], acc[it][cc], 0, 0, 0);
                    acc[it][cc] = __builtin_amdgcn_mfma_f32_16x16x32_bf16(pf1, vf[u][cc][1], acc[it][cc], 0, 0, 0);
                }
            }
        }
    }

    // ---- softmax denominators: reduce across quads, share via LDS ----
    {
        float v = accl;
        v += __shfl_xor(v, 16, 64);
        v += __shfl_xor(v, 32, 64);
        if (quad == 0) lred[w * 16 + ln] = v;
    }
    __syncthreads();

    // ---- store obb bf16 (xt_addr swizzle) ----
    #pragma unroll
    for (int it = 0; it < 4; ++it) {
        float linv[4];
        #pragma unroll
        for (int r = 0; r < 4; ++r) linv[r] = 1.f / lred[it * 16 + quad * 4 + r];
        #pragma unroll
        for (int cc = 0; cc < 4; ++cc) {
            const int c = w * 64 + cc * 16 + ln;
            #pragma unroll
            for (int r = 0; r < 4; ++r) {
                const int i = i0 + it * 16 + quad * 4 + r;
                obb[xt_addr(b, i, c)] = f2b(acc[it][cc][r] * linv[r]);
            }
        }
    }
}

// ---------------------------------------------------------------------------
// Kernel 3: final projection — pure MFMA, no LDS.
// ---------------------------------------------------------------------------
__global__ __launch_bounds__(256, 4)
void proj_kernel(const unsigned short* __restrict__ obb,
                 const unsigned short* __restrict__ wsw,
                 const float* __restrict__ bfb, float* __restrict__ out)
{
    const int it = blockIdx.x;           // 64 i-tiles
    const int ot = blockIdx.y;           // 4 o-tiles
    const int b  = blockIdx.z;
    const int t  = threadIdx.x;
    const int w  = t >> 6;
    const int q  = (t >> 4) & 3;
    const int ln = t & 15;
    const int lofs = (q * 16 + ln) * 8;

    short8 af[8];
    const size_t abase = (size_t)((b * 256 + it * 4 + w) * 8) * 512;
    #pragma unroll
    for (int kk = 0; kk < 8; ++kk)
        af[kk] = *(const short8*)(obb + abase + (size_t)kk * 512 + lofs);

    const int ibase = it * 64 + w * 16;
    #pragma unroll
    for (int oq = 0; oq < 4; ++oq) {
        f32x4 acc = {0.f, 0.f, 0.f, 0.f};
        const int og = 20 + ot * 4 + oq;
        #pragma unroll
        for (int kk = 0; kk < 8; ++kk) {
            short8 bfr = *(const short8*)(wsw + (size_t)(og * 8 + kk) * 512 + lofs);
            acc = __builtin_amdgcn_mfma_f32_16x16x32_bf16(af[kk], bfr, acc, 0, 0, 0);
        }
        const int o = ot * 64 + oq * 16 + ln;
        const float bias = bfb[o];
        float4 s = {acc[0] + bias, acc[1] + bias, acc[2] + bias, acc[3] + bias};
        *(float4*)(out + (size_t)(b * 256 + o) * 4096 + ibase + q * 4) = s;
    }
}

// ---------------------------------------------------------------------------
extern "C" void kernel_launch(void* const* d_in, const int* in_sizes, int n_in,
                              void* d_out, int out_size, void* d_ws, size_t ws_size,
                              hipStream_t stream)
{
    const float* x  = (const float*)d_in[0];
    const float* Wq = (const float*)d_in[1];
    const float* bq = (const float*)d_in[2];
    const float* Wk = (const float*)d_in[3];
    const float* bk = (const float*)d_in[4];
    const float* Wv = (const float*)d_in[5];
    const float* bv = (const float*)d_in[6];
    const float* Wf = (const float*)d_in[7];
    const float* bf = (const float*)d_in[8];
    float* out = (float*)d_out;

    // workspace (shorts)
    unsigned short* qb  = (unsigned short*)d_ws;                  // 8*4096*32
    unsigned short* kb  = qb + (size_t)BATCH * NPOS * CQK;
    unsigned short* vb  = kb + (size_t)BATCH * NPOS * CQK;        // 8*256*4096
    unsigned short* wsw = vb + (size_t)BATCH * CCH * NPOS;        // 36*8*512
    unsigned short* obb = wsw + (size_t)36 * 8 * 512;             // 8*4096*256

    wprep_kernel<<<36, 256, 0, stream>>>(Wq, Wk, Wv, Wf, wsw);
    qkv_kernel<<<dim3(64, 8), 256, 0, stream>>>(x, wsw, bq, bk, bv, qb, kb, vb);
    attn_kernel<<<512, 256, 0, stream>>>(qb, kb, vb, obb);
    proj_kernel<<<dim3(64, 4, 8), 256, 0, stream>>>(obb, wsw, bf, out);
}